// Round 2
// baseline (345.588 us; speedup 1.0000x reference)
//
#include <hip/hip_runtime.h>

#define NN 19        // nodes
#define NT 4096
#define LAT 512
#define HID 2048
#define NE 342       // edges
#define ATS 32       // transposed-activation row stride (floats), 128B aligned

// ============================================================================
// agg1 (fused): build M = I + adjacency-count matrix (19x19) from edge_idx,
// publish M to ws, and compute h0 = M @ z, written transposed [512][ATS].
// Handles edge buffer stored as int64 (pairs of int32) or int32, detected
// on device: int64 values in [0,19) have all-zero odd words.
// ============================================================================
__global__ __launch_bounds__(512) void agg1_kernel(const float* __restrict__ z,
                                                   const int* __restrict__ eidx,
                                                   float* __restrict__ h0t,
                                                   float* __restrict__ Mout) {
    __shared__ int cnt[NN * NN];
    __shared__ float M[NN * NN];
    __shared__ int nzflag;
    const int t = threadIdx.x;
    if (t == 0) nzflag = 0;
    for (int i = t; i < NN * NN; i += 512) cnt[i] = 0;
    __syncthreads();
    if (t < 128 && eidx[2 * t + 1] != 0) atomicOr(&nzflag, 1);
    __syncthreads();
    const bool i64 = (nzflag == 0);
    if (t < NE) {
        const int s = i64 ? eidx[2 * t] : eidx[t];
        const int d = i64 ? eidx[2 * NE + 2 * t] : eidx[NE + t];
        atomicAdd(&cnt[d * NN + s], 1);
    }
    __syncthreads();
    for (int i = t; i < NN * NN; i += 512) {
        const float v = (float)cnt[i] + ((i / NN) == (i % NN) ? 1.f : 0.f);
        M[i] = v;
        Mout[i] = v;
    }
    __syncthreads();
    // aggregation: thread t owns feature column t
    float zv[NN];
#pragma unroll
    for (int i = 0; i < NN; ++i) zv[i] = z[i * LAT + t];
#pragma unroll
    for (int d = 0; d < NN; ++d) {
        float acc = 0.f;
#pragma unroll
        for (int s = 0; s < NN; ++s) acc = fmaf(M[d * NN + s], zv[s], acc);
        h0t[t * ATS + d] = acc;
    }
}

// ============================================================================
// skinny GEMM partial: part[chunk][19][N] = At[19, K-chunk] @ W[K-chunk, N]
// At transposed [K][ATS]. A-chunk staged to LDS (broadcast reads).
// Each thread owns 2 columns (float2 weight loads), k-loop unrolled 8
// -> 8 float2 loads (64 B/lane) in flight for latency hiding.
// BK must be a multiple of 8 and <= 128.
// ============================================================================
__global__ __launch_bounds__(256) void gemm19p(const float* __restrict__ At,
                                               const float* __restrict__ W,
                                               float* __restrict__ part,
                                               int N, int BK) {
    __shared__ float sA[128 * ATS];  // up to BK=128 rows of A
    const int k0 = blockIdx.y * BK;
    // cooperative stage of A chunk: BK*ATS floats = BK*8 float4
    for (int idx = threadIdx.x; idx < BK * (ATS / 4); idx += 256)
        ((float4*)sA)[idx] = ((const float4*)(At + (size_t)k0 * ATS))[idx];
    __syncthreads();

    const int n2 = blockIdx.x * 256 + threadIdx.x;  // column-pair index
    const float* __restrict__ w = W + (size_t)k0 * N + 2 * n2;
    float2 acc[NN];
#pragma unroll
    for (int i = 0; i < NN; ++i) acc[i] = make_float2(0.f, 0.f);

    for (int kk = 0; kk < BK; kk += 8) {
        float2 wb[8];
#pragma unroll
        for (int u = 0; u < 8; ++u)
            wb[u] = *(const float2*)(w + (size_t)(kk + u) * N);
#pragma unroll
        for (int u = 0; u < 8; ++u) {
            const float* ak = sA + (kk + u) * ATS;
#pragma unroll
            for (int i = 0; i < NN; ++i) {
                const float av = ak[i];
                acc[i].x = fmaf(av, wb[u].x, acc[i].x);
                acc[i].y = fmaf(av, wb[u].y, acc[i].y);
            }
        }
    }
    float* __restrict__ p = part + (size_t)(blockIdx.y * NN) * N + 2 * n2;
#pragma unroll
    for (int i = 0; i < NN; ++i) *(float2*)(p + (size_t)i * N) = acc[i];
}

// ---------- reduce partials + bias + relu, write transposed ----------
__global__ __launch_bounds__(256) void gemm19_reduce_relu_t(const float* __restrict__ part,
                                                            const float* __restrict__ bias,
                                                            float* __restrict__ outT,
                                                            int N, int nchunk) {
    const int n = blockIdx.x * 256 + threadIdx.x;
    const float b = bias[n];
    float s[NN];
#pragma unroll
    for (int i = 0; i < NN; ++i) s[i] = b;
    for (int c = 0; c < nchunk; ++c) {
        const float* __restrict__ p = part + (size_t)(c * NN) * N + n;
#pragma unroll
        for (int i = 0; i < NN; ++i) s[i] += p[(size_t)i * N];
    }
#pragma unroll
    for (int i = 0; i < NN; ++i) outT[n * ATS + i] = s[i] > 0.f ? s[i] : 0.f;
}

// ---------- reduce partials + bias + relu + M-aggregation (fused agg2) ----------
__global__ __launch_bounds__(256) void reduce_relu_agg_t(const float* __restrict__ part,
                                                         const float* __restrict__ bias,
                                                         const float* __restrict__ Mg,
                                                         float* __restrict__ outT,
                                                         int N, int nchunk) {
    __shared__ float M[NN * NN];
    const int t = threadIdx.x;
    for (int i = t; i < NN * NN; i += 256) M[i] = Mg[i];
    __syncthreads();
    const int n = blockIdx.x * 256 + t;
    const float b = bias[n];
    float s[NN];
#pragma unroll
    for (int i = 0; i < NN; ++i) s[i] = b;
    for (int c = 0; c < nchunk; ++c) {
        const float* __restrict__ p = part + (size_t)(c * NN) * N + n;
#pragma unroll
        for (int i = 0; i < NN; ++i) s[i] += p[(size_t)i * N];
    }
#pragma unroll
    for (int i = 0; i < NN; ++i) s[i] = s[i] > 0.f ? s[i] : 0.f;  // inter-layer relu
#pragma unroll
    for (int d = 0; d < NN; ++d) {
        float acc = 0.f;
#pragma unroll
        for (int sI = 0; sI < NN; ++sI) acc = fmaf(M[d * NN + sI], s[sI], acc);
        outT[n * ATS + d] = acc;
    }
}

// ---------- reduce partials + bias (no relu), row-major [19][N] to output ----------
__global__ __launch_bounds__(256) void gemm19_reduce_out(const float* __restrict__ part,
                                                         const float* __restrict__ bias,
                                                         float* __restrict__ out,
                                                         int N, int nchunk) {
    const int n = blockIdx.x * 256 + threadIdx.x;
    const float b = bias[n];
#pragma unroll
    for (int i = 0; i < NN; ++i) {
        float s = b;
        for (int c = 0; c < nchunk; ++c)
            s += part[(size_t)(c * NN + i) * N + n];
        out[(size_t)i * N + n] = s;
    }
}

// ---------- classifier partial: part[chunk][512] = flat[chunk] @ Wc1[chunk,512] ----------
// 256 threads cover all 512 columns as float2; unroll 8 (64 B/lane in flight).
__global__ __launch_bounds__(256) void cls_partial(const float* __restrict__ flat,
                                                   const float* __restrict__ Wc1,
                                                   float* __restrict__ part,
                                                   int BK) {
    const int n2 = threadIdx.x;
    const int k0 = blockIdx.x * BK;
    const float* __restrict__ w = Wc1 + (size_t)k0 * LAT + 2 * n2;
    const float* __restrict__ f = flat + k0;
    float2 a0 = make_float2(0.f, 0.f), a1 = a0, a2 = a0, a3 = a0;
    for (int k = 0; k < BK; k += 8) {
        float2 wb[8];
        float fv[8];
#pragma unroll
        for (int u = 0; u < 8; ++u) wb[u] = *(const float2*)(w + (size_t)(k + u) * LAT);
#pragma unroll
        for (int u = 0; u < 8; ++u) fv[u] = f[k + u];
#pragma unroll
        for (int u = 0; u < 8; ++u) {
            float2& A = ((u & 3) == 0) ? a0 : ((u & 3) == 1) ? a1 : ((u & 3) == 2) ? a2 : a3;
            A.x = fmaf(fv[u], wb[u].x, A.x);
            A.y = fmaf(fv[u], wb[u].y, A.y);
        }
    }
    float2 r;
    r.x = (a0.x + a1.x) + (a2.x + a3.x);
    r.y = (a0.y + a1.y) + (a2.y + a3.y);
    *(float2*)(part + (size_t)blockIdx.x * LAT + 2 * n2) = r;
}

// ---------- classifier reduce stage 1: 256 chunks -> 16 group sums ----------
__global__ __launch_bounds__(256) void cls_reduce(const float* __restrict__ part,
                                                  float* __restrict__ part2) {
    const int g = blockIdx.x;
    const int n2 = threadIdx.x;
    float2 acc = make_float2(0.f, 0.f);
#pragma unroll
    for (int c = 0; c < 16; ++c) {
        const float2 v = *(const float2*)(part + (size_t)(g * 16 + c) * LAT + 2 * n2);
        acc.x += v.x;
        acc.y += v.y;
    }
    *(float2*)(part2 + (size_t)g * LAT + 2 * n2) = acc;
}

// ---------- classifier finish ----------
__global__ __launch_bounds__(512) void cls_final(const float* __restrict__ part2,
                                                 const float* __restrict__ bc1,
                                                 const float* __restrict__ Wc2,
                                                 const float* __restrict__ bc2,
                                                 float* __restrict__ out) {
    __shared__ float red[512];
    const int t = threadIdx.x;
    float s = bc1[t];
#pragma unroll
    for (int g = 0; g < 16; ++g) s += part2[(size_t)g * LAT + t];
    red[t] = s * Wc2[t];
    __syncthreads();
    for (int off = 256; off > 0; off >>= 1) {
        if (t < off) red[t] += red[t + off];
        __syncthreads();
    }
    if (t == 0) {
        const float x = red[0] + bc2[0];
        out[0] = 1.f / (1.f + expf(-x));
    }
}

extern "C" void kernel_launch(void* const* d_in, const int* in_sizes, int n_in,
                              void* d_out, int out_size, void* d_ws, size_t ws_size,
                              hipStream_t stream) {
    const float* z   = (const float*)d_in[0];
    const int*   ei  = (const int*)d_in[1];
    const float* W1a = (const float*)d_in[2];
    const float* b1a = (const float*)d_in[3];
    const float* W1b = (const float*)d_in[4];
    const float* b1b = (const float*)d_in[5];
    const float* W2a = (const float*)d_in[6];
    const float* b2a = (const float*)d_in[7];
    const float* W2b = (const float*)d_in[8];
    const float* b2b = (const float*)d_in[9];
    const float* Wc1 = (const float*)d_in[10];
    const float* bc1 = (const float*)d_in[11];
    const float* Wc2 = (const float*)d_in[12];
    const float* bc2 = (const float*)d_in[13];
    float* out = (float*)d_out;
    float* ws  = (float*)d_ws;

    // workspace layout (float offsets)
    float* Mws  = ws + 0;          // 361
    float* h0t  = ws + 4096;       // 512*32  = 16384
    float* t1t  = ws + 24576;      // 2048*32 = 65536
    float* h2t  = ws + 98304;      // 2048*32 = 65536
    float* t2t  = ws + 180224;     // 4096*32 = 131072
    float* part = ws + 1048576;    // up to 32*19*4096 = 2,490,368 floats
    float* part2 = ws + 4194304;   // 16*512 = 8192

    // GIN layer 1:  h0 = M @ z ; h1 = relu(h0@W1a+b1a)@W1b + b1b
    agg1_kernel<<<1, 512, 0, stream>>>(z, ei, h0t, Mws);
    gemm19p<<<dim3(4, 16), 256, 0, stream>>>(h0t, W1a, part, HID, 32);    // K=512
    gemm19_reduce_relu_t<<<8, 256, 0, stream>>>(part, b1a, t1t, HID, 16);
    gemm19p<<<dim3(4, 32), 256, 0, stream>>>(t1t, W1b, part, HID, 64);    // K=2048
    // fused: reduce + bias + inter-layer relu + agg2 (M @ .)
    reduce_relu_agg_t<<<8, 256, 0, stream>>>(part, b1b, Mws, h2t, HID, 32);

    // GIN layer 2: sig = relu(h2@W2a+b2a)@W2b + b2b
    gemm19p<<<dim3(8, 16), 256, 0, stream>>>(h2t, W2a, part, NT, 128);    // K=2048
    gemm19_reduce_relu_t<<<16, 256, 0, stream>>>(part, b2a, t2t, NT, 16);
    gemm19p<<<dim3(8, 32), 256, 0, stream>>>(t2t, W2b, part, NT, 128);    // K=4096
    gemm19_reduce_out<<<16, 256, 0, stream>>>(part, b2b, out + 1, NT, 32);

    // classifier: flat[77824] @ Wc1[77824,512]; 77824 = 256*304
    cls_partial<<<256, 256, 0, stream>>>(out + 1, Wc1, part, 304);
    cls_reduce<<<16, 256, 0, stream>>>(part, part2);
    cls_final<<<1, 512, 0, stream>>>(part2, bc1, Wc2, bc2, out);
}

// Round 3
// 187.616 us; speedup vs baseline: 1.8420x; 1.8420x over previous
//
#include <hip/hip_runtime.h>

#define NN 19        // nodes
#define NT 4096
#define LAT 512
#define HID 2048
#define NE 342       // edges

// ============================================================================
// agg1 (fused): build M = I + adjacency-count matrix (19x19) from edge_idx,
// publish M to ws, and compute h0 = M @ z, row-major [19][512].
// Edge buffer may be int64 (pairs of int32) or int32; detected on device:
// int64 values in [0,19) have all-zero odd words.
// ============================================================================
__global__ __launch_bounds__(512) void agg1_kernel(const float* __restrict__ z,
                                                   const int* __restrict__ eidx,
                                                   float* __restrict__ h0,
                                                   float* __restrict__ Mout) {
    __shared__ int cnt[NN * NN];
    __shared__ float M[NN * NN];
    __shared__ int nzflag;
    const int t = threadIdx.x;
    if (t == 0) nzflag = 0;
    for (int i = t; i < NN * NN; i += 512) cnt[i] = 0;
    __syncthreads();
    if (t < 128 && eidx[2 * t + 1] != 0) atomicOr(&nzflag, 1);
    __syncthreads();
    const bool i64 = (nzflag == 0);
    if (t < NE) {
        const int s = i64 ? eidx[2 * t] : eidx[t];
        const int d = i64 ? eidx[2 * NE + 2 * t] : eidx[NE + t];
        atomicAdd(&cnt[d * NN + s], 1);
    }
    __syncthreads();
    for (int i = t; i < NN * NN; i += 512) {
        const float v = (float)cnt[i] + ((i / NN) == (i % NN) ? 1.f : 0.f);
        M[i] = v;
        Mout[i] = v;
    }
    __syncthreads();
    float zv[NN];
#pragma unroll
    for (int i = 0; i < NN; ++i) zv[i] = z[i * LAT + t];
#pragma unroll
    for (int d = 0; d < NN; ++d) {
        float acc = 0.f;
#pragma unroll
        for (int s = 0; s < NN; ++s) acc = fmaf(M[d * NN + s], zv[s], acc);
        h0[d * LAT + t] = acc;
    }
}

// ============================================================================
// skinny GEMM partial: part[chunk][19][N] = A[19, K-chunk] @ W[K-chunk, N]
// A row-major [19][K]; chunk of A transpose-staged into padded LDS.
// Each thread owns 2 columns (float2 weight loads), k unrolled 8.
// ============================================================================
template <int BK>
__global__ __launch_bounds__(256) void gemm19p(const float* __restrict__ A,
                                               const float* __restrict__ W,
                                               float* __restrict__ part,
                                               int N) {
    __shared__ float sA[BK][20];  // padded: stride 20 dodges bank conflicts
    const int K = gridDim.y * BK;
    const int k0 = blockIdx.y * BK;
    for (int idx = threadIdx.x; idx < NN * BK; idx += 256) {
        const int i = idx / BK, c = idx % BK;
        sA[c][i] = A[(size_t)i * K + k0 + c];
    }
    __syncthreads();

    const int col = 2 * (blockIdx.x * 256 + threadIdx.x);
    const float* __restrict__ w = W + (size_t)k0 * N + col;
    float2 acc[NN];
#pragma unroll
    for (int i = 0; i < NN; ++i) acc[i] = make_float2(0.f, 0.f);

    for (int kk = 0; kk < BK; kk += 8) {
        float2 wb[8];
#pragma unroll
        for (int u = 0; u < 8; ++u)
            wb[u] = *(const float2*)(w + (size_t)(kk + u) * N);
#pragma unroll
        for (int u = 0; u < 8; ++u) {
#pragma unroll
            for (int i = 0; i < NN; ++i) {
                const float av = sA[kk + u][i];
                acc[i].x = fmaf(av, wb[u].x, acc[i].x);
                acc[i].y = fmaf(av, wb[u].y, acc[i].y);
            }
        }
    }
    float* __restrict__ p = part + (size_t)(blockIdx.y * NN) * N + col;
#pragma unroll
    for (int i = 0; i < NN; ++i) *(float2*)(p + (size_t)i * N) = acc[i];
}

// ---------- reduce partials + bias + relu -> [19][N] row-major ----------
// thread -> (row i, col-quad n4); float4 loads: nchunk*16B in flight per lane
__global__ __launch_bounds__(256) void reduce_relu(const float* __restrict__ part,
                                                   const float* __restrict__ bias,
                                                   float* __restrict__ out,
                                                   int N4, int nchunk) {
    const int f = blockIdx.x * 256 + threadIdx.x;
    const int i = f / N4, n4 = f % N4;
    const float4 b = ((const float4*)bias)[n4];
    float4 s = b;
    const float4* __restrict__ p = (const float4*)part + (size_t)i * N4 + n4;
    for (int c = 0; c < nchunk; ++c) {
        const float4 v = p[(size_t)c * NN * N4];
        s.x += v.x; s.y += v.y; s.z += v.z; s.w += v.w;
    }
    s.x = s.x > 0.f ? s.x : 0.f;
    s.y = s.y > 0.f ? s.y : 0.f;
    s.z = s.z > 0.f ? s.z : 0.f;
    s.w = s.w > 0.f ? s.w : 0.f;
    ((float4*)out)[(size_t)i * N4 + n4] = s;
}

// ---------- reduce partials + bias (no relu) -> d_out (scalar stores: out+1
// is only 4B-aligned, so no float4 stores here) ----------
__global__ __launch_bounds__(256) void reduce_out(const float* __restrict__ part,
                                                  const float* __restrict__ bias,
                                                  float* __restrict__ out,
                                                  int N4, int nchunk) {
    const int f = blockIdx.x * 256 + threadIdx.x;
    const int i = f / N4, n4 = f % N4;
    const float4 b = ((const float4*)bias)[n4];
    float4 s = b;
    const float4* __restrict__ p = (const float4*)part + (size_t)i * N4 + n4;
    for (int c = 0; c < nchunk; ++c) {
        const float4 v = p[(size_t)c * NN * N4];
        s.x += v.x; s.y += v.y; s.z += v.z; s.w += v.w;
    }
    float* __restrict__ o = out + ((size_t)i * N4 + n4) * 4;
    o[0] = s.x; o[1] = s.y; o[2] = s.z; o[3] = s.w;
}

// ---------- agg2: out[d][n] = sum_s M[d][s] * h[s][n]  (h already relu'd) ----
__global__ __launch_bounds__(256) void agg19(const float* __restrict__ h,
                                             const float* __restrict__ Mg,
                                             float* __restrict__ out,
                                             int N4) {
    __shared__ float M[NN * NN];
    const int t = threadIdx.x;
    for (int i = t; i < NN * NN; i += 256) M[i] = Mg[i];
    __syncthreads();
    const int f = blockIdx.x * 256 + t;
    const int d = f / N4, n4 = f % N4;
    float4 acc = make_float4(0.f, 0.f, 0.f, 0.f);
#pragma unroll
    for (int s = 0; s < NN; ++s) {
        const float m = M[d * NN + s];
        const float4 v = ((const float4*)h)[(size_t)s * N4 + n4];
        acc.x = fmaf(m, v.x, acc.x);
        acc.y = fmaf(m, v.y, acc.y);
        acc.z = fmaf(m, v.z, acc.z);
        acc.w = fmaf(m, v.w, acc.w);
    }
    ((float4*)out)[(size_t)d * N4 + n4] = acc;
}

// ---------- classifier partial: part[chunk][512] = flat[chunk] @ Wc1 ----------
// 256 threads: n4 = t&127 (col quad), kp = t>>7 (k parity); float4 weight
// loads, 8 in flight (128 B/lane); parity halves combined through LDS.
__global__ __launch_bounds__(256) void cls_partial(const float* __restrict__ flat,
                                                   const float* __restrict__ Wc1,
                                                   float* __restrict__ part,
                                                   int BK) {
    __shared__ float4 comb[128];
    const int t = threadIdx.x;
    const int n4 = t & 127, kp = t >> 7;
    const int k0 = blockIdx.x * BK;
    const float4* __restrict__ w = (const float4*)Wc1 + (size_t)k0 * 128 + n4;
    const float* __restrict__ f = flat + k0;
    float4 acc = make_float4(0.f, 0.f, 0.f, 0.f);
    for (int k = kp; k < BK; k += 16) {
        float4 wb[8];
        float fv[8];
#pragma unroll
        for (int u = 0; u < 8; ++u) wb[u] = w[(size_t)(k + 2 * u) * 128];
#pragma unroll
        for (int u = 0; u < 8; ++u) fv[u] = f[k + 2 * u];
#pragma unroll
        for (int u = 0; u < 8; ++u) {
            acc.x = fmaf(fv[u], wb[u].x, acc.x);
            acc.y = fmaf(fv[u], wb[u].y, acc.y);
            acc.z = fmaf(fv[u], wb[u].z, acc.z);
            acc.w = fmaf(fv[u], wb[u].w, acc.w);
        }
    }
    if (kp) comb[n4] = acc;
    __syncthreads();
    if (!kp) {
        const float4 o = comb[n4];
        acc.x += o.x; acc.y += o.y; acc.z += o.z; acc.w += o.w;
        ((float4*)part)[(size_t)blockIdx.x * 128 + n4] = acc;
    }
}

// ---------- classifier reduce stage 1: 256 chunks -> 16 group sums ----------
__global__ __launch_bounds__(256) void cls_reduce(const float* __restrict__ part,
                                                  float* __restrict__ part2) {
    const int g = blockIdx.x;
    const int t = threadIdx.x;
    float2 acc = make_float2(0.f, 0.f);
#pragma unroll
    for (int c = 0; c < 16; ++c) {
        const float2 v = *(const float2*)(part + (size_t)(g * 16 + c) * LAT + 2 * t);
        acc.x += v.x;
        acc.y += v.y;
    }
    *(float2*)(part2 + (size_t)g * LAT + 2 * t) = acc;
}

// ---------- classifier finish ----------
__global__ __launch_bounds__(512) void cls_final(const float* __restrict__ part2,
                                                 const float* __restrict__ bc1,
                                                 const float* __restrict__ Wc2,
                                                 const float* __restrict__ bc2,
                                                 float* __restrict__ out) {
    __shared__ float red[512];
    const int t = threadIdx.x;
    float s = bc1[t];
#pragma unroll
    for (int g = 0; g < 16; ++g) s += part2[(size_t)g * LAT + t];
    red[t] = s * Wc2[t];
    __syncthreads();
    for (int off = 256; off > 0; off >>= 1) {
        if (t < off) red[t] += red[t + off];
        __syncthreads();
    }
    if (t == 0) {
        const float x = red[0] + bc2[0];
        out[0] = 1.f / (1.f + expf(-x));
    }
}

extern "C" void kernel_launch(void* const* d_in, const int* in_sizes, int n_in,
                              void* d_out, int out_size, void* d_ws, size_t ws_size,
                              hipStream_t stream) {
    const float* z   = (const float*)d_in[0];
    const int*   ei  = (const int*)d_in[1];
    const float* W1a = (const float*)d_in[2];
    const float* b1a = (const float*)d_in[3];
    const float* W1b = (const float*)d_in[4];
    const float* b1b = (const float*)d_in[5];
    const float* W2a = (const float*)d_in[6];
    const float* b2a = (const float*)d_in[7];
    const float* W2b = (const float*)d_in[8];
    const float* b2b = (const float*)d_in[9];
    const float* Wc1 = (const float*)d_in[10];
    const float* bc1 = (const float*)d_in[11];
    const float* Wc2 = (const float*)d_in[12];
    const float* bc2 = (const float*)d_in[13];
    float* out = (float*)d_out;
    float* ws  = (float*)d_ws;

    // workspace layout (float offsets)
    float* Mws   = ws + 0;        // 361
    float* h0    = ws + 1024;     // 19*512
    float* h1a   = ws + 16384;    // 19*2048
    float* h1r   = ws + 65536;    // 19*2048
    float* h2    = ws + 114688;   // 19*2048
    float* t2    = ws + 163840;   // 19*4096
    float* part  = ws + 262144;   // up to 32*19*4096 = 2,490,368
    float* part2 = ws + 3145728;  // 16*512

    // GIN layer 1: h0 = M@z ; h1 = relu(relu(h0@W1a+b1a)@W1b + b1b)
    agg1_kernel<<<1, 512, 0, stream>>>(z, ei, h0, Mws);
    gemm19p<32><<<dim3(4, 16), 256, 0, stream>>>(h0, W1a, part, HID);     // K=512
    reduce_relu<<<38, 256, 0, stream>>>(part, b1a, h1a, HID / 4, 16);
    gemm19p<64><<<dim3(4, 32), 256, 0, stream>>>(h1a, W1b, part, HID);    // K=2048
    reduce_relu<<<38, 256, 0, stream>>>(part, b1b, h1r, HID / 4, 32);     // inter-layer relu
    agg19<<<38, 256, 0, stream>>>(h1r, Mws, h2, HID / 4);

    // GIN layer 2: sig = relu(h2@W2a+b2a)@W2b + b2b
    gemm19p<128><<<dim3(8, 16), 256, 0, stream>>>(h2, W2a, part, NT);     // K=2048
    reduce_relu<<<76, 256, 0, stream>>>(part, b2a, t2, NT / 4, 16);
    gemm19p<128><<<dim3(8, 32), 256, 0, stream>>>(t2, W2b, part, NT);     // K=4096
    reduce_out<<<76, 256, 0, stream>>>(part, b2b, out + 1, NT / 4, 32);

    // classifier: flat[77824] @ Wc1[77824,512]; 77824 = 256*304
    cls_partial<<<256, 256, 0, stream>>>(out + 1, Wc1, part, 304);
    cls_reduce<<<16, 256, 0, stream>>>(part, part2);
    cls_final<<<1, 512, 0, stream>>>(part2, bc1, Wc2, bc2, out);
}